// Round 1
// baseline (943.359 us; speedup 1.0000x reference)
//
#include <hip/hip_runtime.h>

// LSTM2: B=8192, T=60, F=158, H=32, 2 layers, head on final cell states.
// One persistent block per 32 batch rows; all weights transposed in LDS.

constexpr int Bn = 8192, Tn = 60, Fn = 158, Hn = 32, Gn = 128;
constexpr int BT = 32;        // batch tile per block
constexpr int THREADS = 256;  // 4 waves

// LDS layout (float offsets)
constexpr int oW0  = 0;        // Wih0^T padded: 160 x 128 = 20480
constexpr int oWh0 = 20480;    // 32 x 128 = 4096
constexpr int oWi1 = 24576;    // 4096
constexpr int oWh1 = 28672;    // 4096
constexpr int oR   = 32768;    // union{ Xt: 32 x 164 = 5248 ; G: 32 x 132 = 4224 }
constexpr int oH1  = 38016;    // 32 x 36 = 1152
constexpr int oH2  = 39168;    // 1152
constexpr int SMEM_FLOATS = 40320;  // 161280 bytes

__device__ __forceinline__ float sigm_(float x) {
    return __fdividef(1.f, 1.f + __expf(-x));
}
__device__ __forceinline__ float tanh_(float x) {
    // 1 - 2/(e^{2x}+1); correct limits at +/-inf of exp
    return 1.f - __fdividef(2.f, __expf(2.f * x) + 1.f);
}

__device__ __forceinline__ void loadq(const float* sp, int sStride, const float* wp, int k,
                                      float4 (&sv)[4], float4 (&wv)[4]) {
#pragma unroll
    for (int i = 0; i < 4; ++i) sv[i] = *(const float4*)(sp + i * sStride + k);
#pragma unroll
    for (int j = 0; j < 4; ++j) wv[j] = *(const float4*)(wp + (k + j) * Gn);
}

__device__ __forceinline__ void fmaq(float (&acc)[4][4], const float4 (&sv)[4], const float4 (&wv)[4]) {
#pragma unroll
    for (int i = 0; i < 4; ++i) {
        acc[i][0] = fmaf(sv[i].x, wv[0].x, acc[i][0]);
        acc[i][1] = fmaf(sv[i].x, wv[0].y, acc[i][1]);
        acc[i][2] = fmaf(sv[i].x, wv[0].z, acc[i][2]);
        acc[i][3] = fmaf(sv[i].x, wv[0].w, acc[i][3]);
        acc[i][0] = fmaf(sv[i].y, wv[1].x, acc[i][0]);
        acc[i][1] = fmaf(sv[i].y, wv[1].y, acc[i][1]);
        acc[i][2] = fmaf(sv[i].y, wv[1].z, acc[i][2]);
        acc[i][3] = fmaf(sv[i].y, wv[1].w, acc[i][3]);
        acc[i][0] = fmaf(sv[i].z, wv[2].x, acc[i][0]);
        acc[i][1] = fmaf(sv[i].z, wv[2].y, acc[i][1]);
        acc[i][2] = fmaf(sv[i].z, wv[2].z, acc[i][2]);
        acc[i][3] = fmaf(sv[i].z, wv[2].w, acc[i][3]);
        acc[i][0] = fmaf(sv[i].w, wv[3].x, acc[i][0]);
        acc[i][1] = fmaf(sv[i].w, wv[3].y, acc[i][1]);
        acc[i][2] = fmaf(sv[i].w, wv[3].z, acc[i][2]);
        acc[i][3] = fmaf(sv[i].w, wv[3].w, acc[i][3]);
    }
}

// acc[i][n] += sum_k S[bB+i][k] * W[k][gB+n], K = 4*NQ. 2-stage k-quad pipeline.
// Deliberately over-reads one quad past the end (stays inside smem; values unused).
template <int NQ>
__device__ __forceinline__ void gemm(float (&acc)[4][4], const float* S, int sStride,
                                     const float* W, int bB, int gB) {
    const float* sp = S + bB * sStride;
    const float* wp = W + gB;
    float4 sv[4], wv[4], svn[4], wvn[4];
    loadq(sp, sStride, wp, 0, sv, wv);
#pragma unroll 1
    for (int kq = 0; kq < NQ; kq += 2) {
        loadq(sp, sStride, wp, (kq + 1) * 4, svn, wvn);
        fmaq(acc, sv, wv);
        loadq(sp, sStride, wp, (kq + 2) * 4, sv, wv);  // over-read on last iter: harmless
        fmaq(acc, svn, wvn);
    }
}

__global__ __launch_bounds__(THREADS, 1) void lstm2_kernel(
    const float* __restrict__ x,
    const float* __restrict__ Wih0, const float* __restrict__ Whh0,
    const float* __restrict__ Wih1, const float* __restrict__ Whh1,
    const float* __restrict__ W1, const float* __restrict__ b1,
    const float* __restrict__ W2, float* __restrict__ out) {
    extern __shared__ float sm[];
    const int tid = threadIdx.x;
    const int bBase = blockIdx.x * BT;

    float* sW0 = sm + oW0;
    float* sWh0 = sm + oWh0;
    float* sWi1 = sm + oWi1;
    float* sWh1 = sm + oWh1;
    float* sR = sm + oR;
    float* sH1 = sm + oH1;
    float* sH2 = sm + oH2;

    // ---- stage weights, transposed to [k][g] (linear LDS writes, gathered global reads)
    for (int i = tid; i < Fn * Gn; i += THREADS) {
        int g = i & 127, k = i >> 7;
        sW0[i] = Wih0[g * Fn + k];
    }
    sW0[Fn * Gn + tid] = 0.f;  // zero pad rows k=158,159 (256 entries)
    for (int i = tid; i < Hn * Gn; i += THREADS) {
        int g = i & 127, k = i >> 7;
        sWh0[i] = Whh0[g * Hn + k];
        sWi1[i] = Wih1[g * Hn + k];
        sWh1[i] = Whh1[g * Hn + k];
    }
    for (int i = tid; i < 1152; i += THREADS) {
        sH1[i] = 0.f;
        sH2[i] = 0.f;
    }

    // GEMM lane mapping: 4 waves = 2(M) x 2(N); in-wave 4(lm) x 16(ln); 4x4 accs
    const int wave = tid >> 6, lane = tid & 63;
    const int bB = (wave & 1) * 16 + (lane >> 4) * 4;   // batch row base
    const int gB = (wave >> 1) * 64 + (lane & 15) * 4;  // gate col base
    // update-phase mapping: thread owns (ub, uj..uj+3)
    const int ub = tid >> 3, uj = (tid & 7) * 4;

    float c1[4] = {0.f, 0.f, 0.f, 0.f}, c2[4] = {0.f, 0.f, 0.f, 0.f};

    // x prefetch registers: 32 rows x 79 float2 = 2528
    float2 xr[10];
    auto loadX = [&](int t) {
#pragma unroll
        for (int r = 0; r < 10; ++r) {
            int i = tid + r * THREADS;
            if (i < 2528) {
                int b = i / 79, c = i - b * 79;
                xr[r] = ((const float2*)x)[(size_t)((bBase + b) * Tn + t) * 79 + c];
            }
        }
    };

    loadX(0);
    __syncthreads();  // weights + state staged

    for (int t = 0; t < Tn; ++t) {
        // ---- store Xt (stride 164), zero f=158..159 pads (G writes clobber them)
#pragma unroll
        for (int r = 0; r < 10; ++r) {
            int i = tid + r * THREADS;
            if (i < 2528) {
                int b = i / 79, c = i - b * 79;
                *(float2*)(sR + b * 164 + 2 * c) = xr[r];
            }
        }
        if (tid < 64) sR[(tid >> 1) * 164 + 158 + (tid & 1)] = 0.f;
        __syncthreads();  // A: Xt ready

        loadX(t < Tn - 1 ? t + 1 : Tn - 1);  // prefetch next step (in flight during GEMMs)

        float acc[4][4] = {};
        gemm<40>(acc, sR, 164, sW0, bB, gB);   // x part, K=160 (padded)
        gemm<8>(acc, sH1, 36, sWh0, bB, gB);   // h1 part, K=32
        __syncthreads();  // B: all reads of sR/sH1 done
#pragma unroll
        for (int i = 0; i < 4; ++i)
            *(float4*)(sR + (bB + i) * 132 + gB) =
                make_float4(acc[i][0], acc[i][1], acc[i][2], acc[i][3]);
        __syncthreads();  // C: G1 visible

        {  // ---- update layer 1
            float4 ig = *(const float4*)(sR + ub * 132 + uj);
            float4 fg = *(const float4*)(sR + ub * 132 + uj + 32);
            float4 gg = *(const float4*)(sR + ub * 132 + uj + 64);
            float4 og = *(const float4*)(sR + ub * 132 + uj + 96);
            float iv[4] = {ig.x, ig.y, ig.z, ig.w}, fv[4] = {fg.x, fg.y, fg.z, fg.w};
            float gv[4] = {gg.x, gg.y, gg.z, gg.w}, ov[4] = {og.x, og.y, og.z, og.w};
            float h[4];
#pragma unroll
            for (int n = 0; n < 4; ++n) {
                c1[n] = sigm_(fv[n]) * c1[n] + sigm_(iv[n]) * tanh_(gv[n]);
                h[n] = sigm_(ov[n]) * tanh_(c1[n]);
            }
            *(float4*)(sH1 + ub * 36 + uj) = make_float4(h[0], h[1], h[2], h[3]);
        }
        __syncthreads();  // D: h1 ready, G1 consumed (sR free)

        float acc2[4][4] = {};
        gemm<8>(acc2, sH1, 36, sWi1, bB, gB);
        gemm<8>(acc2, sH2, 36, sWh1, bB, gB);
        // G2 write races with nothing: GEMM2 reads only sH1/sH2
#pragma unroll
        for (int i = 0; i < 4; ++i)
            *(float4*)(sR + (bB + i) * 132 + gB) =
                make_float4(acc2[i][0], acc2[i][1], acc2[i][2], acc2[i][3]);
        __syncthreads();  // E: G2 visible, all sH2 reads done

        {  // ---- update layer 2
            float4 ig = *(const float4*)(sR + ub * 132 + uj);
            float4 fg = *(const float4*)(sR + ub * 132 + uj + 32);
            float4 gg = *(const float4*)(sR + ub * 132 + uj + 64);
            float4 og = *(const float4*)(sR + ub * 132 + uj + 96);
            float iv[4] = {ig.x, ig.y, ig.z, ig.w}, fv[4] = {fg.x, fg.y, fg.z, fg.w};
            float gv[4] = {gg.x, gg.y, gg.z, gg.w}, ov[4] = {og.x, og.y, og.z, og.w};
            float h[4];
#pragma unroll
            for (int n = 0; n < 4; ++n) {
                c2[n] = sigm_(fv[n]) * c2[n] + sigm_(iv[n]) * tanh_(gv[n]);
                h[n] = sigm_(ov[n]) * tanh_(c2[n]);
            }
            *(float4*)(sH2 + ub * 36 + uj) = make_float4(h[0], h[1], h[2], h[3]);
        }
        __syncthreads();  // F: h2 ready; sR free for next Xt
    }

    // ---- head: y[l,b] = relu(c @ W1^T + b1) @ W2^T  on final c1, c2
    float* sC = sR;  // stride 33, [2][32][33]
#pragma unroll
    for (int n = 0; n < 4; ++n) {
        sC[ub * 33 + uj + n] = c1[n];
        sC[1056 + ub * 33 + uj + n] = c2[n];
    }
    __syncthreads();
    if (tid < 64) {
        int l = tid >> 5, b = tid & 31;
        const float* cc = sC + l * 1056 + b * 33;
        float y = 0.f;
#pragma unroll 1
        for (int q = 0; q < 16; ++q) {
            float s = b1[q];
#pragma unroll
            for (int j = 0; j < 32; ++j) s = fmaf(cc[j], W1[q * 32 + j], s);
            y = fmaf(fmaxf(s, 0.f), W2[q], y);
        }
        out[l * Bn + bBase + b] = y;
    }
}

extern "C" void kernel_launch(void* const* d_in, const int* in_sizes, int n_in,
                              void* d_out, int out_size, void* d_ws, size_t ws_size,
                              hipStream_t stream) {
    const float* x    = (const float*)d_in[0];
    const float* Wih0 = (const float*)d_in[1];
    const float* Whh0 = (const float*)d_in[2];
    const float* Wih1 = (const float*)d_in[3];
    const float* Whh1 = (const float*)d_in[4];
    const float* W1   = (const float*)d_in[5];
    const float* b1   = (const float*)d_in[6];
    const float* W2   = (const float*)d_in[7];
    float* out = (float*)d_out;

    size_t smem = SMEM_FLOATS * sizeof(float);  // 161280 B
    lstm2_kernel<<<Bn / BT, THREADS, smem, stream>>>(x, Wih0, Whh0, Wih1, Whh1, W1, b1, W2, out);
}

// Round 2
// 774.135 us; speedup vs baseline: 1.2186x; 1.2186x over previous
//
#include <hip/hip_runtime.h>

// LSTM2: B=8192, T=60, F=158, H=32, 2 layers, head on final cell states.
// Two-kernel plan: phase1 = xg = x @ Wih0^T via bf16 hi/lo-split MFMA into d_ws,
// phase2 = recurrent scan (K=96 VALU per step), 512 blocks x 16 rows, 2 blocks/CU.

constexpr int Bn = 8192, Tn = 60, Fn = 158, Hn = 32, Gn = 128;

typedef __attribute__((ext_vector_type(8))) short short8;
typedef __attribute__((ext_vector_type(4))) float floatx4;

__device__ __forceinline__ float sigm_(float x) {
    return __fdividef(1.f, 1.f + __expf(-x));
}
__device__ __forceinline__ float tanh_(float x) {
    return 1.f - __fdividef(2.f, __expf(2.f * x) + 1.f);
}
__device__ __forceinline__ unsigned short bf16r(float x) {
    unsigned u = __float_as_uint(x);
    return (unsigned short)((u + 0x7fffu + ((u >> 16) & 1u)) >> 16);
}
__device__ __forceinline__ float bf16f(unsigned short h) {
    return __uint_as_float(((unsigned)h) << 16);
}

// ============================ Phase 1: xg GEMM ============================
// M = B*T = 491520 (x rows are exactly m = b*60+t), N = 128, K = 158 (pad 160).
// Block: 64 M-rows, 256 threads (4 waves x 32 N-cols). hi/lo bf16 split.

constexpr int P1S = 168;  // LDS row stride in shorts

__global__ __launch_bounds__(256, 2) void xg_gemm_kernel(
    const float* __restrict__ x, const float* __restrict__ Wih0,
    float* __restrict__ xg) {
    __shared__ unsigned short sHi[64 * P1S];
    __shared__ unsigned short sLo[64 * P1S];
    const int tid = threadIdx.x;
    const int wave = tid >> 6, lane = tid & 63;
    const int l15 = lane & 15, quad = lane >> 4;
    const size_t m0 = (size_t)blockIdx.x * 64;

    // ---- stage x tile (contiguous 64*158 floats) as hi/lo bf16, stride 168
    const float* xt = x + m0 * Fn;
#pragma unroll
    for (int r = 0; r < 40; ++r) {
        int idx = tid + r * 256;
        if (idx < 2528) {  // 2528 float4 = 10112... (64*158/4 = 2528)
            float4 v = ((const float4*)xt)[idx];
            float vv[4] = {v.x, v.y, v.z, v.w};
#pragma unroll
            for (int u = 0; u < 4; ++u) {
                int e = idx * 4 + u;
                int m = e / Fn, f = e - m * Fn;
                unsigned short hi = bf16r(vv[u]);
                unsigned short lo = bf16r(vv[u] - bf16f(hi));
                sHi[m * P1S + f] = hi;
                sLo[m * P1S + f] = lo;
            }
        }
    }
    // zero pad f = 158..167
    for (int i = tid; i < 64 * 10; i += 256) {
        int m = i / 10, f = Fn + (i - m * 10);
        sHi[m * P1S + f] = 0;
        sLo[m * P1S + f] = 0;
    }

    // ---- B fragments from global (L2-hot): B[k][n] = Wih0[n][k], n = gate col
    // lane holds n = wave*32 + nt*16 + l15, k = ks*32 + quad*8 + j
    short8 bh[2][5], bl[2][5];
#pragma unroll
    for (int nt = 0; nt < 2; ++nt) {
        int g = wave * 32 + nt * 16 + l15;
#pragma unroll
        for (int ks = 0; ks < 5; ++ks) {
#pragma unroll
            for (int j = 0; j < 8; ++j) {
                int k = ks * 32 + quad * 8 + j;
                float w = (k < Fn) ? Wih0[g * Fn + k] : 0.f;
                unsigned short hi = bf16r(w);
                unsigned short lo = bf16r(w - bf16f(hi));
                bh[nt][ks][j] = (short)hi;
                bl[nt][ks][j] = (short)lo;
            }
        }
    }
    __syncthreads();

    floatx4 acc[4][2] = {};  // 4 M-tiles x 2 N-tiles per wave
#pragma unroll
    for (int ks = 0; ks < 5; ++ks) {
        short8 ah[4], al[4];
#pragma unroll
        for (int mt = 0; mt < 4; ++mt) {
            int off = (mt * 16 + l15) * P1S + ks * 32 + quad * 8;
            ah[mt] = *(const short8*)(sHi + off);
            al[mt] = *(const short8*)(sLo + off);
        }
#pragma unroll
        for (int mt = 0; mt < 4; ++mt)
#pragma unroll
            for (int nt = 0; nt < 2; ++nt) {
                acc[mt][nt] = __builtin_amdgcn_mfma_f32_16x16x32_bf16(
                    ah[mt], bh[nt][ks], acc[mt][nt], 0, 0, 0);
                acc[mt][nt] = __builtin_amdgcn_mfma_f32_16x16x32_bf16(
                    ah[mt], bl[nt][ks], acc[mt][nt], 0, 0, 0);
                acc[mt][nt] = __builtin_amdgcn_mfma_f32_16x16x32_bf16(
                    al[mt], bh[nt][ks], acc[mt][nt], 0, 0, 0);
            }
    }
    // D: col = l15 (+tile), row = quad*4 + reg (+tile)
#pragma unroll
    for (int mt = 0; mt < 4; ++mt)
#pragma unroll
        for (int nt = 0; nt < 2; ++nt) {
            int col = wave * 32 + nt * 16 + l15;
#pragma unroll
            for (int reg = 0; reg < 4; ++reg) {
                size_t row = m0 + mt * 16 + quad * 4 + reg;
                xg[row * Gn + col] = acc[mt][nt][reg];
            }
        }
}

// ============================ Phase 2: recurrence ============================
// 512 blocks x 16 batch rows, 256 threads (4 waves). LDS 62 KB -> 2 blocks/CU.
// LDS float offsets:
constexpr int oWh0 = 0;      // 32x128 = 4096
constexpr int oWi1 = 4096;   // 4096
constexpr int oWh1 = 8192;   // 4096
constexpr int oG   = 12288;  // 16 x 132 = 2112 (head scratch reuses this)
constexpr int oH1  = 14400;  // 16 x 36 = 576
constexpr int oH2  = 14976;  // 576
constexpr int P2_FLOATS = 15552;  // 62208 B

__device__ __forceinline__ void loadq2(const float* sp, const float* wp, int k,
                                       float4 (&sv)[2], float4 (&wv)[4]) {
#pragma unroll
    for (int i = 0; i < 2; ++i) sv[i] = *(const float4*)(sp + i * 36 + k);
#pragma unroll
    for (int j = 0; j < 4; ++j) wv[j] = *(const float4*)(wp + (k + j) * Gn);
}

__device__ __forceinline__ void fmaq2(float (&acc)[2][4], const float4 (&sv)[2],
                                      const float4 (&wv)[4]) {
#pragma unroll
    for (int i = 0; i < 2; ++i) {
        acc[i][0] = fmaf(sv[i].x, wv[0].x, acc[i][0]);
        acc[i][1] = fmaf(sv[i].x, wv[0].y, acc[i][1]);
        acc[i][2] = fmaf(sv[i].x, wv[0].z, acc[i][2]);
        acc[i][3] = fmaf(sv[i].x, wv[0].w, acc[i][3]);
        acc[i][0] = fmaf(sv[i].y, wv[1].x, acc[i][0]);
        acc[i][1] = fmaf(sv[i].y, wv[1].y, acc[i][1]);
        acc[i][2] = fmaf(sv[i].y, wv[1].z, acc[i][2]);
        acc[i][3] = fmaf(sv[i].y, wv[1].w, acc[i][3]);
        acc[i][0] = fmaf(sv[i].z, wv[2].x, acc[i][0]);
        acc[i][1] = fmaf(sv[i].z, wv[2].y, acc[i][1]);
        acc[i][2] = fmaf(sv[i].z, wv[2].z, acc[i][2]);
        acc[i][3] = fmaf(sv[i].z, wv[2].w, acc[i][3]);
        acc[i][0] = fmaf(sv[i].w, wv[3].x, acc[i][0]);
        acc[i][1] = fmaf(sv[i].w, wv[3].y, acc[i][1]);
        acc[i][2] = fmaf(sv[i].w, wv[3].z, acc[i][2]);
        acc[i][3] = fmaf(sv[i].w, wv[3].w, acc[i][3]);
    }
}

// acc[i][n] += sum_k S[rB+i][k] * W[k][gB+n]; 2-stage pipeline, over-reads 1 quad.
template <int NQ>
__device__ __forceinline__ void gemm2(float (&acc)[2][4], const float* S,
                                      const float* W, int rB, int gB) {
    const float* sp = S + rB * 36;
    const float* wp = W + gB;
    float4 sv[2], wv[4], svn[2], wvn[4];
    loadq2(sp, wp, 0, sv, wv);
#pragma unroll 1
    for (int kq = 0; kq < NQ; kq += 2) {
        loadq2(sp, wp, (kq + 1) * 4, svn, wvn);
        fmaq2(acc, sv, wv);
        loadq2(sp, wp, (kq + 2) * 4, sv, wv);  // last over-read: in-bounds, unused
        fmaq2(acc, svn, wvn);
    }
}

__global__ __launch_bounds__(256, 2) void lstm_rec_kernel(
    const float* __restrict__ xg,
    const float* __restrict__ Whh0, const float* __restrict__ Wih1,
    const float* __restrict__ Whh1, const float* __restrict__ W1,
    const float* __restrict__ b1, const float* __restrict__ W2,
    float* __restrict__ out) {
    __shared__ float sm[P2_FLOATS];
    const int tid = threadIdx.x;
    const int bBase = blockIdx.x * 16;
    float* sWh0 = sm + oWh0;
    float* sWi1 = sm + oWi1;
    float* sWh1 = sm + oWh1;
    float* sG = sm + oG;
    float* sH1 = sm + oH1;
    float* sH2 = sm + oH2;

    // stage recurrent weights transposed [k][g]
    for (int i = tid; i < Hn * Gn; i += 256) {
        int g = i & 127, k = i >> 7;
        sWh0[i] = Whh0[g * Hn + k];
        sWi1[i] = Wih1[g * Hn + k];
        sWh1[i] = Whh1[g * Hn + k];
    }
    for (int i = tid; i < 576; i += 256) {
        sH1[i] = 0.f;
        sH2[i] = 0.f;
    }

    // GEMM mapping: 4 waves = 2(M) x 2(N); lane: 4 groups x 2 rows, 16 x 4 cols
    const int wave = tid >> 6, lane = tid & 63;
    const int rB = (wave & 1) * 8 + ((lane >> 4) << 1);  // 2 rows
    const int gB = (wave >> 1) * 64 + (lane & 15) * 4;   // 4 cols
    // update mapping: thread owns (urow, uj..uj+1)
    const int urow = tid >> 4, uj = (tid & 15) * 2;

    float c1[2] = {0.f, 0.f}, c2[2] = {0.f, 0.f};

    // xg pointer: row (bBase+rB+i), addr = (row*60 + t)*128 + gB
    const float* xgp = xg + (size_t)(bBase + rB) * (Tn * Gn) + gB;
    float4 xgA[2], xgB[2];
    xgA[0] = *(const float4*)(xgp);
    xgA[1] = *(const float4*)(xgp + Tn * Gn);
    __syncthreads();

    for (int t = 0; t < Tn; ++t) {
        int tn = (t < Tn - 1) ? t + 1 : Tn - 1;
        xgB[0] = *(const float4*)(xgp + tn * Gn);
        xgB[1] = *(const float4*)(xgp + Tn * Gn + tn * Gn);

        float acc[2][4] = {};
        gemm2<8>(acc, sH1, sWh0, rB, gB);
#pragma unroll
        for (int i = 0; i < 2; ++i) {
            float4 xv = xgA[i];
            *(float4*)(sG + (rB + i) * 132 + gB) =
                make_float4(acc[i][0] + xv.x, acc[i][1] + xv.y,
                            acc[i][2] + xv.z, acc[i][3] + xv.w);
        }
        __syncthreads();  // B1: G1 visible, gemm1 reads done

        {  // update layer 1
            const float* g0 = sG + urow * 132 + uj;
            float2 ig = *(const float2*)(g0);
            float2 fg = *(const float2*)(g0 + 32);
            float2 gg = *(const float2*)(g0 + 64);
            float2 og = *(const float2*)(g0 + 96);
            c1[0] = sigm_(fg.x) * c1[0] + sigm_(ig.x) * tanh_(gg.x);
            c1[1] = sigm_(fg.y) * c1[1] + sigm_(ig.y) * tanh_(gg.y);
            float h0 = sigm_(og.x) * tanh_(c1[0]);
            float h1 = sigm_(og.y) * tanh_(c1[1]);
            *(float2*)(sH1 + urow * 36 + uj) = make_float2(h0, h1);
        }
        __syncthreads();  // B2: h1 ready

        float acc2[2][4] = {};
        gemm2<8>(acc2, sH1, sWi1, rB, gB);
        gemm2<8>(acc2, sH2, sWh1, rB, gB);
#pragma unroll
        for (int i = 0; i < 2; ++i)
            *(float4*)(sG + (rB + i) * 132 + gB) =
                make_float4(acc2[i][0], acc2[i][1], acc2[i][2], acc2[i][3]);
        __syncthreads();  // B3: G2 visible, gemm2 reads done

        {  // update layer 2
            const float* g0 = sG + urow * 132 + uj;
            float2 ig = *(const float2*)(g0);
            float2 fg = *(const float2*)(g0 + 32);
            float2 gg = *(const float2*)(g0 + 64);
            float2 og = *(const float2*)(g0 + 96);
            c2[0] = sigm_(fg.x) * c2[0] + sigm_(ig.x) * tanh_(gg.x);
            c2[1] = sigm_(fg.y) * c2[1] + sigm_(ig.y) * tanh_(gg.y);
            float h0 = sigm_(og.x) * tanh_(c2[0]);
            float h1 = sigm_(og.y) * tanh_(c2[1]);
            *(float2*)(sH2 + urow * 36 + uj) = make_float2(h0, h1);
        }
        __syncthreads();  // B4: h2 ready

        xgA[0] = xgB[0];
        xgA[1] = xgB[1];
    }

    // ---- head on final c1, c2: y = relu(c @ W1^T + b1) @ W2^T
    float* sC = sG;  // [2][16][33]
    *(float2*)(sC + urow * 33 + uj) = make_float2(c1[0], c1[1]);
    *(float2*)(sC + 528 + urow * 33 + uj) = make_float2(c2[0], c2[1]);
    __syncthreads();
    if (tid < 32) {
        int l = tid >> 4, b = tid & 15;
        const float* cc = sC + l * 528 + b * 33;
        float y = 0.f;
#pragma unroll 1
        for (int q = 0; q < 16; ++q) {
            float s = b1[q];
#pragma unroll
            for (int j = 0; j < 32; ++j) s = fmaf(cc[j], W1[q * 32 + j], s);
            y = fmaf(fmaxf(s, 0.f), W2[q], y);
        }
        out[l * Bn + bBase + b] = y;
    }
}

// ===================== Fallback (round-1 fused kernel) =====================
constexpr int F_oW0 = 0, F_oWh0 = 20480, F_oWi1 = 24576, F_oWh1 = 28672;
constexpr int F_oR = 32768, F_oH1 = 38016, F_oH2 = 39168, F_SMEM = 40320;

__device__ __forceinline__ void loadq(const float* sp, int sStride, const float* wp, int k,
                                      float4 (&sv)[4], float4 (&wv)[4]) {
#pragma unroll
    for (int i = 0; i < 4; ++i) sv[i] = *(const float4*)(sp + i * sStride + k);
#pragma unroll
    for (int j = 0; j < 4; ++j) wv[j] = *(const float4*)(wp + (k + j) * Gn);
}
__device__ __forceinline__ void fmaq(float (&acc)[4][4], const float4 (&sv)[4], const float4 (&wv)[4]) {
#pragma unroll
    for (int i = 0; i < 4; ++i) {
        acc[i][0] = fmaf(sv[i].x, wv[0].x, acc[i][0]);
        acc[i][1] = fmaf(sv[i].x, wv[0].y, acc[i][1]);
        acc[i][2] = fmaf(sv[i].x, wv[0].z, acc[i][2]);
        acc[i][3] = fmaf(sv[i].x, wv[0].w, acc[i][3]);
        acc[i][0] = fmaf(sv[i].y, wv[1].x, acc[i][0]);
        acc[i][1] = fmaf(sv[i].y, wv[1].y, acc[i][1]);
        acc[i][2] = fmaf(sv[i].y, wv[1].z, acc[i][2]);
        acc[i][3] = fmaf(sv[i].y, wv[1].w, acc[i][3]);
        acc[i][0] = fmaf(sv[i].z, wv[2].x, acc[i][0]);
        acc[i][1] = fmaf(sv[i].z, wv[2].y, acc[i][1]);
        acc[i][2] = fmaf(sv[i].z, wv[2].z, acc[i][2]);
        acc[i][3] = fmaf(sv[i].z, wv[2].w, acc[i][3]);
        acc[i][0] = fmaf(sv[i].w, wv[3].x, acc[i][0]);
        acc[i][1] = fmaf(sv[i].w, wv[3].y, acc[i][1]);
        acc[i][2] = fmaf(sv[i].w, wv[3].z, acc[i][2]);
        acc[i][3] = fmaf(sv[i].w, wv[3].w, acc[i][3]);
    }
}
template <int NQ>
__device__ __forceinline__ void gemmF(float (&acc)[4][4], const float* S, int sStride,
                                      const float* W, int bB, int gB) {
    const float* sp = S + bB * sStride;
    const float* wp = W + gB;
    float4 sv[4], wv[4], svn[4], wvn[4];
    loadq(sp, sStride, wp, 0, sv, wv);
#pragma unroll 1
    for (int kq = 0; kq < NQ; kq += 2) {
        loadq(sp, sStride, wp, (kq + 1) * 4, svn, wvn);
        fmaq(acc, sv, wv);
        loadq(sp, sStride, wp, (kq + 2) * 4, sv, wv);
        fmaq(acc, svn, wvn);
    }
}

__global__ __launch_bounds__(256, 1) void lstm2_kernel(
    const float* __restrict__ x,
    const float* __restrict__ Wih0, const float* __restrict__ Whh0,
    const float* __restrict__ Wih1, const float* __restrict__ Whh1,
    const float* __restrict__ W1, const float* __restrict__ b1,
    const float* __restrict__ W2, float* __restrict__ out) {
    extern __shared__ float sm[];
    const int tid = threadIdx.x;
    const int bBase = blockIdx.x * 32;
    float* sW0 = sm + F_oW0;
    float* sWh0 = sm + F_oWh0;
    float* sWi1 = sm + F_oWi1;
    float* sWh1 = sm + F_oWh1;
    float* sR = sm + F_oR;
    float* sH1 = sm + F_oH1;
    float* sH2 = sm + F_oH2;

    for (int i = tid; i < Fn * Gn; i += 256) {
        int g = i & 127, k = i >> 7;
        sW0[i] = Wih0[g * Fn + k];
    }
    sW0[Fn * Gn + tid] = 0.f;
    for (int i = tid; i < Hn * Gn; i += 256) {
        int g = i & 127, k = i >> 7;
        sWh0[i] = Whh0[g * Hn + k];
        sWi1[i] = Wih1[g * Hn + k];
        sWh1[i] = Whh1[g * Hn + k];
    }
    for (int i = tid; i < 1152; i += 256) {
        sH1[i] = 0.f;
        sH2[i] = 0.f;
    }
    const int wave = tid >> 6, lane = tid & 63;
    const int bB = (wave & 1) * 16 + (lane >> 4) * 4;
    const int gB = (wave >> 1) * 64 + (lane & 15) * 4;
    const int ub = tid >> 3, uj = (tid & 7) * 4;
    float c1[4] = {0.f, 0.f, 0.f, 0.f}, c2[4] = {0.f, 0.f, 0.f, 0.f};
    float2 xr[10];
    auto loadX = [&](int t) {
#pragma unroll
        for (int r = 0; r < 10; ++r) {
            int i = tid + r * 256;
            if (i < 2528) {
                int b = i / 79, c = i - b * 79;
                xr[r] = ((const float2*)x)[(size_t)((bBase + b) * Tn + t) * 79 + c];
            }
        }
    };
    loadX(0);
    __syncthreads();
    for (int t = 0; t < Tn; ++t) {
#pragma unroll
        for (int r = 0; r < 10; ++r) {
            int i = tid + r * 256;
            if (i < 2528) {
                int b = i / 79, c = i - b * 79;
                *(float2*)(sR + b * 164 + 2 * c) = xr[r];
            }
        }
        if (tid < 64) sR[(tid >> 1) * 164 + 158 + (tid & 1)] = 0.f;
        __syncthreads();
        loadX(t < Tn - 1 ? t + 1 : Tn - 1);
        float acc[4][4] = {};
        gemmF<40>(acc, sR, 164, sW0, bB, gB);
        gemmF<8>(acc, sH1, 36, sWh0, bB, gB);
        __syncthreads();
#pragma unroll
        for (int i = 0; i < 4; ++i)
            *(float4*)(sR + (bB + i) * 132 + gB) =
                make_float4(acc[i][0], acc[i][1], acc[i][2], acc[i][3]);
        __syncthreads();
        {
            float4 ig = *(const float4*)(sR + ub * 132 + uj);
            float4 fg = *(const float4*)(sR + ub * 132 + uj + 32);
            float4 gg = *(const float4*)(sR + ub * 132 + uj + 64);
            float4 og = *(const float4*)(sR + ub * 132 + uj + 96);
            float iv[4] = {ig.x, ig.y, ig.z, ig.w}, fv[4] = {fg.x, fg.y, fg.z, fg.w};
            float gv[4] = {gg.x, gg.y, gg.z, gg.w}, ov[4] = {og.x, og.y, og.z, og.w};
            float h[4];
#pragma unroll
            for (int n = 0; n < 4; ++n) {
                c1[n] = sigm_(fv[n]) * c1[n] + sigm_(iv[n]) * tanh_(gv[n]);
                h[n] = sigm_(ov[n]) * tanh_(c1[n]);
            }
            *(float4*)(sH1 + ub * 36 + uj) = make_float4(h[0], h[1], h[2], h[3]);
        }
        __syncthreads();
        float acc2[4][4] = {};
        gemmF<8>(acc2, sH1, 36, sWi1, bB, gB);
        gemmF<8>(acc2, sH2, 36, sWh1, bB, gB);
#pragma unroll
        for (int i = 0; i < 4; ++i)
            *(float4*)(sR + (bB + i) * 132 + gB) =
                make_float4(acc2[i][0], acc2[i][1], acc2[i][2], acc2[i][3]);
        __syncthreads();
        {
            float4 ig = *(const float4*)(sR + ub * 132 + uj);
            float4 fg = *(const float4*)(sR + ub * 132 + uj + 32);
            float4 gg = *(const float4*)(sR + ub * 132 + uj + 64);
            float4 og = *(const float4*)(sR + ub * 132 + uj + 96);
            float iv[4] = {ig.x, ig.y, ig.z, ig.w}, fv[4] = {fg.x, fg.y, fg.z, fg.w};
            float gv[4] = {gg.x, gg.y, gg.z, gg.w}, ov[4] = {og.x, og.y, og.z, og.w};
            float h[4];
#pragma unroll
            for (int n = 0; n < 4; ++n) {
                c2[n] = sigm_(fv[n]) * c2[n] + sigm_(iv[n]) * tanh_(gv[n]);
                h[n] = sigm_(ov[n]) * tanh_(c2[n]);
            }
            *(float4*)(sH2 + ub * 36 + uj) = make_float4(h[0], h[1], h[2], h[3]);
        }
        __syncthreads();
    }
    float* sC = sR;
#pragma unroll
    for (int n = 0; n < 4; ++n) {
        sC[ub * 33 + uj + n] = c1[n];
        sC[1056 + ub * 33 + uj + n] = c2[n];
    }
    __syncthreads();
    if (tid < 64) {
        int l = tid >> 5, b = tid & 31;
        const float* cc = sC + l * 1056 + b * 33;
        float y = 0.f;
#pragma unroll 1
        for (int q = 0; q < 16; ++q) {
            float s = b1[q];
#pragma unroll
            for (int j = 0; j < 32; ++j) s = fmaf(cc[j], W1[q * 32 + j], s);
            y = fmaf(fmaxf(s, 0.f), W2[q], y);
        }
        out[l * Bn + bBase + b] = y;
    }
}

extern "C" void kernel_launch(void* const* d_in, const int* in_sizes, int n_in,
                              void* d_out, int out_size, void* d_ws, size_t ws_size,
                              hipStream_t stream) {
    const float* x    = (const float*)d_in[0];
    const float* Wih0 = (const float*)d_in[1];
    const float* Whh0 = (const float*)d_in[2];
    const float* Wih1 = (const float*)d_in[3];
    const float* Whh1 = (const float*)d_in[4];
    const float* W1   = (const float*)d_in[5];
    const float* b1   = (const float*)d_in[6];
    const float* W2   = (const float*)d_in[7];
    float* out = (float*)d_out;

    const size_t need = (size_t)Bn * Tn * Gn * sizeof(float);  // 251,658,240 B
    if (ws_size >= need) {
        float* xg = (float*)d_ws;
        xg_gemm_kernel<<<(Bn * Tn) / 64, 256, 0, stream>>>(x, Wih0, xg);
        lstm_rec_kernel<<<Bn / 16, 256, 0, stream>>>(xg, Whh0, Wih1, Whh1, W1, b1, W2, out);
    } else {
        lstm2_kernel<<<Bn / 32, 256, 161280, stream>>>(x, Wih0, Whh0, Wih1, Whh1, W1, b1,
                                                       W2, out);
    }
}

// Round 3
// 687.663 us; speedup vs baseline: 1.3718x; 1.1257x over previous
//
#include <hip/hip_runtime.h>

// LSTM2: B=8192, T=60, F=158, H=32, 2 layers, head on final cell states.
// R3: phase0 wfrag (precompute Wih0 B-fragments) -> phase1 xg2 (LDS-free MFMA
// GEMM, x read once) -> phase2 rec (MFMA recurrence, weights in registers).

constexpr int Bn = 8192, Tn = 60, Fn = 158, Hn = 32, Gn = 128;

typedef __attribute__((ext_vector_type(8))) short short8;
typedef __attribute__((ext_vector_type(4))) float floatx4;

__device__ __forceinline__ float sigm_(float x) {
    return __fdividef(1.f, 1.f + __expf(-x));
}
__device__ __forceinline__ float tanh_(float x) {
    return 1.f - __fdividef(2.f, __expf(2.f * x) + 1.f);
}
__device__ __forceinline__ unsigned short bf16r(float x) {
    unsigned u = __float_as_uint(x);
    return (unsigned short)((u + 0x7fffu + ((u >> 16) & 1u)) >> 16);
}
__device__ __forceinline__ float bf16f(unsigned short h) {
    return __uint_as_float(((unsigned)h) << 16);
}
__device__ __forceinline__ void cvt8(const float* v, short8& hi, short8& lo) {
#pragma unroll
    for (int j = 0; j < 8; ++j) {
        unsigned short h = bf16r(v[j]);
        hi[j] = (short)h;
        lo[j] = (short)bf16r(v[j] - bf16f(h));
    }
}

// ====================== Phase 0: Wih0 B-fragment precompute ======================
// FB[ks][ntg][lane][16 shorts: 8 hi, 8 lo]; entry = fragment for
// n = ntg*16 + (lane&15), k = ks*32 + (lane>>4)*8 + j.  5*8*64*16 shorts = 80 KB.
__global__ void wfrag_kernel(const float* __restrict__ Wih0,
                             unsigned short* __restrict__ FB) {
    int e = blockIdx.x * 256 + threadIdx.x;
    if (e >= 2560) return;
    int ks = e >> 9, rem = e & 511;
    int ntg = rem >> 6, lane = rem & 63;
    int quad = lane >> 4, l15 = lane & 15;
    int n = ntg * 16 + l15;
    unsigned short* dst = FB + (size_t)e * 16;
#pragma unroll
    for (int j = 0; j < 8; ++j) {
        int k = ks * 32 + quad * 8 + j;
        float w = (k < Fn) ? Wih0[n * Fn + k] : 0.f;
        unsigned short hi = bf16r(w);
        dst[j] = hi;
        dst[8 + j] = bf16r(w - bf16f(hi));
    }
}

// ====================== Phase 1: xg = x @ Wih0^T (MFMA) ======================
// Grid 7680 x 256. Wave w owns 16 M-rows (m0+w*16..+15), all 8 N-tiles.
// No LDS, no barriers: A loaded from global per-lane, B from FB (L2-hot).
__global__ __launch_bounds__(256, 2) void xg2_kernel(
    const float* __restrict__ x, const unsigned short* __restrict__ FB,
    float* __restrict__ xg) {
    const int tid = threadIdx.x;
    const int wave = tid >> 6, lane = tid & 63;
    const int quad = lane >> 4, l15 = lane & 15;
    const size_t m0 = (size_t)blockIdx.x * 64 + wave * 16;
    const float* arow = x + (m0 + l15) * Fn;

    floatx4 acc[8] = {};
#pragma unroll
    for (int ks = 0; ks < 5; ++ks) {
        const int k0 = ks * 32 + quad * 8;
        const bool tail = (k0 == 152);  // k=158,159 out of range -> zero
        float2 p0 = *(const float2*)(arow + k0);
        float2 p1 = *(const float2*)(arow + k0 + 2);
        float2 p2 = *(const float2*)(arow + k0 + 4);
        float2 p3 = tail ? make_float2(0.f, 0.f) : *(const float2*)(arow + k0 + 6);
        float av[8] = {p0.x, p0.y, p1.x, p1.y, p2.x, p2.y, p3.x, p3.y};
        short8 ah, al;
        cvt8(av, ah, al);
        const unsigned short* fb = FB + ((size_t)(ks * 8) * 64 + lane) * 16;
#pragma unroll
        for (int ntg = 0; ntg < 8; ++ntg) {
            short8 bh = *(const short8*)(fb + (size_t)ntg * 1024);
            short8 bl = *(const short8*)(fb + (size_t)ntg * 1024 + 8);
            acc[ntg] = __builtin_amdgcn_mfma_f32_16x16x32_bf16(ah, bh, acc[ntg], 0, 0, 0);
            acc[ntg] = __builtin_amdgcn_mfma_f32_16x16x32_bf16(ah, bl, acc[ntg], 0, 0, 0);
            acc[ntg] = __builtin_amdgcn_mfma_f32_16x16x32_bf16(al, bh, acc[ntg], 0, 0, 0);
        }
    }
#pragma unroll
    for (int ntg = 0; ntg < 8; ++ntg)
#pragma unroll
        for (int reg = 0; reg < 4; ++reg)
            xg[(m0 + quad * 4 + reg) * Gn + ntg * 16 + l15] = acc[ntg][reg];
}

// ====================== Phase 2: recurrence (MFMA) ======================
// 512 blocks x 16 batch rows, 256 threads (4 waves, each 2 N-tiles = 32 gate cols).
// Weights as register B-fragments; h1/h2 in LDS as bf16 hi/lo, A-frag layout.
constexpr int SK = 40;  // h-buffer short stride (pad)

__global__ __launch_bounds__(256, 2) void lstm_rec_kernel(
    const float* __restrict__ xg,
    const float* __restrict__ Whh0, const float* __restrict__ Wih1,
    const float* __restrict__ Whh1, const float* __restrict__ W1,
    const float* __restrict__ b1, const float* __restrict__ W2,
    float* __restrict__ out) {
    __shared__ float sG[16 * 132];                 // gate scratch (also head scratch)
    __shared__ unsigned short sH1h[16 * SK];       // h1 hi
    __shared__ unsigned short sH1l[16 * SK];       // h1 lo
    __shared__ unsigned short sH2h[16 * SK];       // h2 hi
    __shared__ unsigned short sH2l[16 * SK];       // h2 lo

    const int tid = threadIdx.x;
    const int wave = tid >> 6, lane = tid & 63;
    const int quad = lane >> 4, l15 = lane & 15;
    const int bBase = blockIdx.x * 16;

    // ---- weight B-fragments into registers: [mat][nt][hi/lo]
    // mat 0 = Whh0, 1 = Wih1, 2 = Whh1; each [128 gate rows][32 k]
    short8 bW[3][2][2];
    const float* Wp[3] = {Whh0, Wih1, Whh1};
#pragma unroll
    for (int m = 0; m < 3; ++m)
#pragma unroll
        for (int nt = 0; nt < 2; ++nt) {
            int n = wave * 32 + nt * 16 + l15;
            const float* wp = Wp[m] + n * Hn + quad * 8;
            float4 q0 = *(const float4*)(wp);
            float4 q1 = *(const float4*)(wp + 4);
            float wv[8] = {q0.x, q0.y, q0.z, q0.w, q1.x, q1.y, q1.z, q1.w};
            cvt8(wv, bW[m][nt][0], bW[m][nt][1]);
        }

    // zero h state
    for (int i = tid; i < 16 * SK; i += 256) {
        sH1h[i] = 0; sH1l[i] = 0; sH2h[i] = 0; sH2l[i] = 0;
    }

    // xg row pointers for this lane's 4 D-rows
    const float* rowptr[4];
#pragma unroll
    for (int reg = 0; reg < 4; ++reg)
        rowptr[reg] = xg + (size_t)(bBase + quad * 4 + reg) * (Tn * Gn) + wave * 32 + l15;

    const int aOff = l15 * SK + quad * 8;  // A-fragment short offset
    const int urow = tid >> 4, uj = (tid & 15) * 2;  // update mapping
    float c1x = 0.f, c1y = 0.f, c2x = 0.f, c2y = 0.f;

    float xgA[8], xgB[8];
#pragma unroll
    for (int nt = 0; nt < 2; ++nt)
#pragma unroll
        for (int reg = 0; reg < 4; ++reg)
            xgA[nt * 4 + reg] = rowptr[reg][nt * 16];
    __syncthreads();

    for (int t = 0; t < Tn; ++t) {
        // prefetch next-step xg
        int tn = (t < Tn - 1) ? t + 1 : Tn - 1;
#pragma unroll
        for (int nt = 0; nt < 2; ++nt)
#pragma unroll
            for (int reg = 0; reg < 4; ++reg)
                xgB[nt * 4 + reg] = rowptr[reg][tn * Gn + nt * 16];

        // ---- layer-1 gates: h1_old @ Whh0^T + xg
        {
            short8 a1h = *(const short8*)(sH1h + aOff);
            short8 a1l = *(const short8*)(sH1l + aOff);
            floatx4 acc[2] = {};
#pragma unroll
            for (int nt = 0; nt < 2; ++nt) {
                acc[nt] = __builtin_amdgcn_mfma_f32_16x16x32_bf16(a1h, bW[0][nt][0], acc[nt], 0, 0, 0);
                acc[nt] = __builtin_amdgcn_mfma_f32_16x16x32_bf16(a1h, bW[0][nt][1], acc[nt], 0, 0, 0);
                acc[nt] = __builtin_amdgcn_mfma_f32_16x16x32_bf16(a1l, bW[0][nt][0], acc[nt], 0, 0, 0);
            }
#pragma unroll
            for (int nt = 0; nt < 2; ++nt)
#pragma unroll
                for (int reg = 0; reg < 4; ++reg)
                    sG[(quad * 4 + reg) * 132 + wave * 32 + nt * 16 + l15] =
                        acc[nt][reg] + xgA[nt * 4 + reg];
        }
        __syncthreads();  // B1: gates1 visible, h1_old reads done

        {  // ---- update layer 1
            const float* g0 = sG + urow * 132 + uj;
            float2 ig = *(const float2*)(g0);
            float2 fg = *(const float2*)(g0 + 32);
            float2 gg = *(const float2*)(g0 + 64);
            float2 og = *(const float2*)(g0 + 96);
            c1x = sigm_(fg.x) * c1x + sigm_(ig.x) * tanh_(gg.x);
            c1y = sigm_(fg.y) * c1y + sigm_(ig.y) * tanh_(gg.y);
            float h0 = sigm_(og.x) * tanh_(c1x);
            float h1v = sigm_(og.y) * tanh_(c1y);
            unsigned short h0h = bf16r(h0), h1h = bf16r(h1v);
            unsigned short h0l = bf16r(h0 - bf16f(h0h)), h1l = bf16r(h1v - bf16f(h1h));
            *(unsigned*)(sH1h + urow * SK + uj) = (unsigned)h0h | ((unsigned)h1h << 16);
            *(unsigned*)(sH1l + urow * SK + uj) = (unsigned)h0l | ((unsigned)h1l << 16);
        }
        __syncthreads();  // B2: h1_new visible

        // ---- layer-2 gates: h1_new @ Wih1^T + h2_old @ Whh1^T
        {
            short8 a1h = *(const short8*)(sH1h + aOff);
            short8 a1l = *(const short8*)(sH1l + aOff);
            short8 a2h = *(const short8*)(sH2h + aOff);
            short8 a2l = *(const short8*)(sH2l + aOff);
            floatx4 acc[2] = {};
#pragma unroll
            for (int nt = 0; nt < 2; ++nt) {
                acc[nt] = __builtin_amdgcn_mfma_f32_16x16x32_bf16(a1h, bW[1][nt][0], acc[nt], 0, 0, 0);
                acc[nt] = __builtin_amdgcn_mfma_f32_16x16x32_bf16(a1h, bW[1][nt][1], acc[nt], 0, 0, 0);
                acc[nt] = __builtin_amdgcn_mfma_f32_16x16x32_bf16(a1l, bW[1][nt][0], acc[nt], 0, 0, 0);
                acc[nt] = __builtin_amdgcn_mfma_f32_16x16x32_bf16(a2h, bW[2][nt][0], acc[nt], 0, 0, 0);
                acc[nt] = __builtin_amdgcn_mfma_f32_16x16x32_bf16(a2h, bW[2][nt][1], acc[nt], 0, 0, 0);
                acc[nt] = __builtin_amdgcn_mfma_f32_16x16x32_bf16(a2l, bW[2][nt][0], acc[nt], 0, 0, 0);
            }
#pragma unroll
            for (int nt = 0; nt < 2; ++nt)
#pragma unroll
                for (int reg = 0; reg < 4; ++reg)
                    sG[(quad * 4 + reg) * 132 + wave * 32 + nt * 16 + l15] = acc[nt][reg];
        }
        __syncthreads();  // B3: gates2 visible, h2_old reads done

        {  // ---- update layer 2
            const float* g0 = sG + urow * 132 + uj;
            float2 ig = *(const float2*)(g0);
            float2 fg = *(const float2*)(g0 + 32);
            float2 gg = *(const float2*)(g0 + 64);
            float2 og = *(const float2*)(g0 + 96);
            c2x = sigm_(fg.x) * c2x + sigm_(ig.x) * tanh_(gg.x);
            c2y = sigm_(fg.y) * c2y + sigm_(ig.y) * tanh_(gg.y);
            float h0 = sigm_(og.x) * tanh_(c2x);
            float h1v = sigm_(og.y) * tanh_(c2y);
            unsigned short h0h = bf16r(h0), h1h = bf16r(h1v);
            unsigned short h0l = bf16r(h0 - bf16f(h0h)), h1l = bf16r(h1v - bf16f(h1h));
            *(unsigned*)(sH2h + urow * SK + uj) = (unsigned)h0h | ((unsigned)h1h << 16);
            *(unsigned*)(sH2l + urow * SK + uj) = (unsigned)h0l | ((unsigned)h1l << 16);
        }
        __syncthreads();  // B4: h2_new visible; sG free

#pragma unroll
        for (int i = 0; i < 8; ++i) xgA[i] = xgB[i];
    }

    // ---- head on final c1, c2: y = relu(c @ W1^T + b1) @ W2^T
    float* sC = sG;  // [2][16][33]
    *(float2*)(sC + urow * 33 + uj) = make_float2(c1x, c1y);
    *(float2*)(sC + 528 + urow * 33 + uj) = make_float2(c2x, c2y);
    __syncthreads();
    if (tid < 32) {
        int l = tid >> 4, b = tid & 15;
        const float* cc = sC + l * 528 + b * 33;
        float y = 0.f;
#pragma unroll 1
        for (int q = 0; q < 16; ++q) {
            float s = b1[q];
#pragma unroll
            for (int j = 0; j < 32; ++j) s = fmaf(cc[j], W1[q * 32 + j], s);
            y = fmaf(fmaxf(s, 0.f), W2[q], y);
        }
        out[l * Bn + bBase + b] = y;
    }
}

// ============== Mid fallback: R2's LDS-staged phase-1 (if ws lacks 80 KB slack) ==============
constexpr int P1S = 168;
__global__ __launch_bounds__(256, 2) void xg_gemm_kernel(
    const float* __restrict__ x, const float* __restrict__ Wih0,
    float* __restrict__ xg) {
    __shared__ unsigned short sHi[64 * P1S];
    __shared__ unsigned short sLo[64 * P1S];
    const int tid = threadIdx.x;
    const int wave = tid >> 6, lane = tid & 63;
    const int l15 = lane & 15, quad = lane >> 4;
    const size_t m0 = (size_t)blockIdx.x * 64;
    const float* xt = x + m0 * Fn;
#pragma unroll
    for (int r = 0; r < 10; ++r) {
        int idx = tid + r * 256;
        if (idx < 2528) {
            float4 v = ((const float4*)xt)[idx];
            float vv[4] = {v.x, v.y, v.z, v.w};
#pragma unroll
            for (int u = 0; u < 4; ++u) {
                int e = idx * 4 + u;
                int m = e / Fn, f = e - m * Fn;
                unsigned short hi = bf16r(vv[u]);
                unsigned short lo = bf16r(vv[u] - bf16f(hi));
                sHi[m * P1S + f] = hi;
                sLo[m * P1S + f] = lo;
            }
        }
    }
    for (int i = tid; i < 64 * 10; i += 256) {
        int m = i / 10, f = Fn + (i - m * 10);
        sHi[m * P1S + f] = 0;
        sLo[m * P1S + f] = 0;
    }
    short8 bh[2][5], bl[2][5];
#pragma unroll
    for (int nt = 0; nt < 2; ++nt) {
        int g = wave * 32 + nt * 16 + l15;
#pragma unroll
        for (int ks = 0; ks < 5; ++ks)
#pragma unroll
            for (int j = 0; j < 8; ++j) {
                int k = ks * 32 + quad * 8 + j;
                float w = (k < Fn) ? Wih0[g * Fn + k] : 0.f;
                unsigned short hi = bf16r(w);
                bh[nt][ks][j] = (short)hi;
                bl[nt][ks][j] = (short)bf16r(w - bf16f(hi));
            }
    }
    __syncthreads();
    floatx4 acc[4][2] = {};
#pragma unroll
    for (int ks = 0; ks < 5; ++ks) {
        short8 ah[4], al[4];
#pragma unroll
        for (int mt = 0; mt < 4; ++mt) {
            int off = (mt * 16 + l15) * P1S + ks * 32 + quad * 8;
            ah[mt] = *(const short8*)(sHi + off);
            al[mt] = *(const short8*)(sLo + off);
        }
#pragma unroll
        for (int mt = 0; mt < 4; ++mt)
#pragma unroll
            for (int nt = 0; nt < 2; ++nt) {
                acc[mt][nt] = __builtin_amdgcn_mfma_f32_16x16x32_bf16(ah[mt], bh[nt][ks], acc[mt][nt], 0, 0, 0);
                acc[mt][nt] = __builtin_amdgcn_mfma_f32_16x16x32_bf16(ah[mt], bl[nt][ks], acc[mt][nt], 0, 0, 0);
                acc[mt][nt] = __builtin_amdgcn_mfma_f32_16x16x32_bf16(al[mt], bh[nt][ks], acc[mt][nt], 0, 0, 0);
            }
    }
#pragma unroll
    for (int mt = 0; mt < 4; ++mt)
#pragma unroll
        for (int nt = 0; nt < 2; ++nt) {
            int col = wave * 32 + nt * 16 + l15;
#pragma unroll
            for (int reg = 0; reg < 4; ++reg)
                xg[(m0 + mt * 16 + quad * 4 + reg) * Gn + col] = acc[mt][nt][reg];
        }
}

// ===================== Ultimate fallback (R1 fused, no ws) =====================
constexpr int F_oW0 = 0, F_oWh0 = 20480, F_oWi1 = 24576, F_oWh1 = 28672;
constexpr int F_oR = 32768, F_oH1 = 38016, F_oH2 = 39168;

__device__ __forceinline__ void loadq(const float* sp, int sStride, const float* wp, int k,
                                      float4 (&sv)[4], float4 (&wv)[4]) {
#pragma unroll
    for (int i = 0; i < 4; ++i) sv[i] = *(const float4*)(sp + i * sStride + k);
#pragma unroll
    for (int j = 0; j < 4; ++j) wv[j] = *(const float4*)(wp + (k + j) * Gn);
}
__device__ __forceinline__ void fmaq(float (&acc)[4][4], const float4 (&sv)[4], const float4 (&wv)[4]) {
#pragma unroll
    for (int i = 0; i < 4; ++i) {
        acc[i][0] = fmaf(sv[i].x, wv[0].x, acc[i][0]);
        acc[i][1] = fmaf(sv[i].x, wv[0].y, acc[i][1]);
        acc[i][2] = fmaf(sv[i].x, wv[0].z, acc[i][2]);
        acc[i][3] = fmaf(sv[i].x, wv[0].w, acc[i][3]);
        acc[i][0] = fmaf(sv[i].y, wv[1].x, acc[i][0]);
        acc[i][1] = fmaf(sv[i].y, wv[1].y, acc[i][1]);
        acc[i][2] = fmaf(sv[i].y, wv[1].z, acc[i][2]);
        acc[i][3] = fmaf(sv[i].y, wv[1].w, acc[i][3]);
        acc[i][0] = fmaf(sv[i].z, wv[2].x, acc[i][0]);
        acc[i][1] = fmaf(sv[i].z, wv[2].y, acc[i][1]);
        acc[i][2] = fmaf(sv[i].z, wv[2].z, acc[i][2]);
        acc[i][3] = fmaf(sv[i].z, wv[2].w, acc[i][3]);
        acc[i][0] = fmaf(sv[i].w, wv[3].x, acc[i][0]);
        acc[i][1] = fmaf(sv[i].w, wv[3].y, acc[i][1]);
        acc[i][2] = fmaf(sv[i].w, wv[3].z, acc[i][2]);
        acc[i][3] = fmaf(sv[i].w, wv[3].w, acc[i][3]);
    }
}
template <int NQ>
__device__ __forceinline__ void gemmF(float (&acc)[4][4], const float* S, int sStride,
                                      const float* W, int bB, int gB) {
    const float* sp = S + bB * sStride;
    const float* wp = W + gB;
    float4 sv[4], wv[4], svn[4], wvn[4];
    loadq(sp, sStride, wp, 0, sv, wv);
#pragma unroll 1
    for (int kq = 0; kq < NQ; kq += 2) {
        loadq(sp, sStride, wp, (kq + 1) * 4, svn, wvn);
        fmaq(acc, sv, wv);
        loadq(sp, sStride, wp, (kq + 2) * 4, sv, wv);
        fmaq(acc, svn, wvn);
    }
}
__global__ __launch_bounds__(256, 1) void lstm2_kernel(
    const float* __restrict__ x,
    const float* __restrict__ Wih0, const float* __restrict__ Whh0,
    const float* __restrict__ Wih1, const float* __restrict__ Whh1,
    const float* __restrict__ W1, const float* __restrict__ b1,
    const float* __restrict__ W2, float* __restrict__ out) {
    extern __shared__ float sm[];
    const int tid = threadIdx.x;
    const int bBase = blockIdx.x * 32;
    float* sW0 = sm + F_oW0;
    float* sWh0 = sm + F_oWh0;
    float* sWi1 = sm + F_oWi1;
    float* sWh1 = sm + F_oWh1;
    float* sR = sm + F_oR;
    float* sH1 = sm + F_oH1;
    float* sH2 = sm + F_oH2;
    for (int i = tid; i < Fn * Gn; i += 256) {
        int g = i & 127, k = i >> 7;
        sW0[i] = Wih0[g * Fn + k];
    }
    sW0[Fn * Gn + tid] = 0.f;
    for (int i = tid; i < Hn * Gn; i += 256) {
        int g = i & 127, k = i >> 7;
        sWh0[i] = Whh0[g * Hn + k];
        sWi1[i] = Wih1[g * Hn + k];
        sWh1[i] = Whh1[g * Hn + k];
    }
    for (int i = tid; i < 1152; i += 256) {
        sH1[i] = 0.f;
        sH2[i] = 0.f;
    }
    const int wave = tid >> 6, lane = tid & 63;
    const int bB = (wave & 1) * 16 + (lane >> 4) * 4;
    const int gB = (wave >> 1) * 64 + (lane & 15) * 4;
    const int ub = tid >> 3, uj = (tid & 7) * 4;
    float c1[4] = {0.f, 0.f, 0.f, 0.f}, c2[4] = {0.f, 0.f, 0.f, 0.f};
    float2 xr[10];
    auto loadX = [&](int t) {
#pragma unroll
        for (int r = 0; r < 10; ++r) {
            int i = tid + r * 256;
            if (i < 2528) {
                int b = i / 79, c = i - b * 79;
                xr[r] = ((const float2*)x)[(size_t)((bBase + b) * Tn + t) * 79 + c];
            }
        }
    };
    loadX(0);
    __syncthreads();
    for (int t = 0; t < Tn; ++t) {
#pragma unroll
        for (int r = 0; r < 10; ++r) {
            int i = tid + r * 256;
            if (i < 2528) {
                int b = i / 79, c = i - b * 79;
                *(float2*)(sR + b * 164 + 2 * c) = xr[r];
            }
        }
        if (tid < 64) sR[(tid >> 1) * 164 + 158 + (tid & 1)] = 0.f;
        __syncthreads();
        loadX(t < Tn - 1 ? t + 1 : Tn - 1);
        float acc[4][4] = {};
        gemmF<40>(acc, sR, 164, sW0, bB, gB);
        gemmF<8>(acc, sH1, 36, sWh0, bB, gB);
        __syncthreads();
#pragma unroll
        for (int i = 0; i < 4; ++i)
            *(float4*)(sR + (bB + i) * 132 + gB) =
                make_float4(acc[i][0], acc[i][1], acc[i][2], acc[i][3]);
        __syncthreads();
        {
            float4 ig = *(const float4*)(sR + ub * 132 + uj);
            float4 fg = *(const float4*)(sR + ub * 132 + uj + 32);
            float4 gg = *(const float4*)(sR + ub * 132 + uj + 64);
            float4 og = *(const float4*)(sR + ub * 132 + uj + 96);
            float iv[4] = {ig.x, ig.y, ig.z, ig.w}, fv[4] = {fg.x, fg.y, fg.z, fg.w};
            float gv[4] = {gg.x, gg.y, gg.z, gg.w}, ov[4] = {og.x, og.y, og.z, og.w};
            float h[4];
#pragma unroll
            for (int n = 0; n < 4; ++n) {
                c1[n] = sigm_(fv[n]) * c1[n] + sigm_(iv[n]) * tanh_(gv[n]);
                h[n] = sigm_(ov[n]) * tanh_(c1[n]);
            }
            *(float4*)(sH1 + ub * 36 + uj) = make_float4(h[0], h[1], h[2], h[3]);
        }
        __syncthreads();
        float acc2[4][4] = {};
        gemmF<8>(acc2, sH1, 36, sWi1, bB, gB);
        gemmF<8>(acc2, sH2, 36, sWh1, bB, gB);
#pragma unroll
        for (int i = 0; i < 4; ++i)
            *(float4*)(sR + (bB + i) * 132 + gB) =
                make_float4(acc2[i][0], acc2[i][1], acc2[i][2], acc2[i][3]);
        __syncthreads();
        {
            float4 ig = *(const float4*)(sR + ub * 132 + uj);
            float4 fg = *(const float4*)(sR + ub * 132 + uj + 32);
            float4 gg = *(const float4*)(sR + ub * 132 + uj + 64);
            float4 og = *(const float4*)(sR + ub * 132 + uj + 96);
            float iv[4] = {ig.x, ig.y, ig.z, ig.w}, fv[4] = {fg.x, fg.y, fg.z, fg.w};
            float gv[4] = {gg.x, gg.y, gg.z, gg.w}, ov[4] = {og.x, og.y, og.z, og.w};
            float h[4];
#pragma unroll
            for (int n = 0; n < 4; ++n) {
                c2[n] = sigm_(fv[n]) * c2[n] + sigm_(iv[n]) * tanh_(gv[n]);
                h[n] = sigm_(ov[n]) * tanh_(c2[n]);
            }
            *(float4*)(sH2 + ub * 36 + uj) = make_float4(h[0], h[1], h[2], h[3]);
        }
        __syncthreads();
    }
    float* sC = sR;
#pragma unroll
    for (int n = 0; n < 4; ++n) {
        sC[ub * 33 + uj + n] = c1[n];
        sC[1056 + ub * 33 + uj + n] = c2[n];
    }
    __syncthreads();
    if (tid < 64) {
        int l = tid >> 5, b = tid & 31;
        const float* cc = sC + l * 1056 + b * 33;
        float y = 0.f;
#pragma unroll 1
        for (int q = 0; q < 16; ++q) {
            float s = b1[q];
#pragma unroll
            for (int j = 0; j < 32; ++j) s = fmaf(cc[j], W1[q * 32 + j], s);
            y = fmaf(fmaxf(s, 0.f), W2[q], y);
        }
        out[l * Bn + bBase + b] = y;
    }
}

extern "C" void kernel_launch(void* const* d_in, const int* in_sizes, int n_in,
                              void* d_out, int out_size, void* d_ws, size_t ws_size,
                              hipStream_t stream) {
    const float* x    = (const float*)d_in[0];
    const float* Wih0 = (const float*)d_in[1];
    const float* Whh0 = (const float*)d_in[2];
    const float* Wih1 = (const float*)d_in[3];
    const float* Whh1 = (const float*)d_in[4];
    const float* W1   = (const float*)d_in[5];
    const float* b1   = (const float*)d_in[6];
    const float* W2   = (const float*)d_in[7];
    float* out = (float*)d_out;

    const size_t xg_bytes = (size_t)Bn * Tn * Gn * sizeof(float);  // 251,658,240
    const size_t fb_bytes = 2560 * 16 * sizeof(unsigned short);    // 81,920

    if (ws_size >= xg_bytes + fb_bytes) {
        unsigned short* FB = (unsigned short*)d_ws;
        float* xg = (float*)((char*)d_ws + fb_bytes);
        wfrag_kernel<<<10, 256, 0, stream>>>(Wih0, FB);
        xg2_kernel<<<(Bn * Tn) / 64, 256, 0, stream>>>(x, FB, xg);
        lstm_rec_kernel<<<Bn / 16, 256, 0, stream>>>(xg, Whh0, Wih1, Whh1, W1, b1, W2, out);
    } else if (ws_size >= xg_bytes) {
        float* xg = (float*)d_ws;
        xg_gemm_kernel<<<(Bn * Tn) / 64, 256, 0, stream>>>(x, Wih0, xg);
        lstm_rec_kernel<<<Bn / 16, 256, 0, stream>>>(xg, Whh0, Wih1, Whh1, W1, b1, W2, out);
    } else {
        lstm2_kernel<<<Bn / 32, 256, 161280, stream>>>(x, Wih0, Whh0, Wih1, Whh1, W1, b1,
                                                       W2, out);
    }
}

// Round 4
// 486.319 us; speedup vs baseline: 1.9398x; 1.4140x over previous
//
#include <hip/hip_runtime.h>

// LSTM2: B=8192, T=60, F=158, H=32, 2 layers, head on final cell states (torch
// h_n[-1]==c_n quirk). R4: single fused kernel. 512 blocks x 16 batch rows,
// 256 threads (4 waves). All weights as register-resident MFMA B-fragments
// (bf16 hi/lo split: a*b ~= ah*bh + ah*bl + al*bh, ~2^-17 rel err). x staged
// per-step into double-buffered LDS A-fragment layout, prefetched 1 step ahead.
// Input projection is fused into the layer-1 gate MFMA (K=160).

constexpr int Bn = 8192, Tn = 60, Fn = 158, Hn = 32, Gn = 128;
constexpr int SKX = 168;  // x-buffer short stride per row (160 + 8 pad)
constexpr int SKH = 40;   // h-buffer short stride per row

typedef __attribute__((ext_vector_type(8))) short short8;
typedef __attribute__((ext_vector_type(4))) float floatx4;

__device__ __forceinline__ float sigm_(float x) {
    return __fdividef(1.f, 1.f + __expf(-x));
}
__device__ __forceinline__ float tanh_(float x) {
    return 1.f - __fdividef(2.f, __expf(2.f * x) + 1.f);
}
__device__ __forceinline__ unsigned short bf16r(float x) {
    unsigned u = __float_as_uint(x);
    return (unsigned short)((u + 0x7fffu + ((u >> 16) & 1u)) >> 16);
}
__device__ __forceinline__ float bf16f(unsigned short h) {
    return __uint_as_float(((unsigned)h) << 16);
}
__device__ __forceinline__ void cvt8(const float* v, short8& hi, short8& lo) {
#pragma unroll
    for (int j = 0; j < 8; ++j) {
        unsigned short h = bf16r(v[j]);
        hi[j] = (short)h;
        lo[j] = (short)bf16r(v[j] - bf16f(h));
    }
}

__global__ __launch_bounds__(256, 2) void lstm2_fused_kernel(
    const float* __restrict__ x,
    const float* __restrict__ Wih0, const float* __restrict__ Whh0,
    const float* __restrict__ Wih1, const float* __restrict__ Whh1,
    const float* __restrict__ W1, const float* __restrict__ b1,
    const float* __restrict__ W2, float* __restrict__ out) {
    // LDS: x double-buffer (A-frag layout, hi/lo), h1/h2 (hi/lo), gate scratch
    __shared__ unsigned short sXh[2 * 16 * SKX];  // 10752 B
    __shared__ unsigned short sXl[2 * 16 * SKX];  // 10752 B
    __shared__ unsigned short sH1h[16 * SKH], sH1l[16 * SKH];  // 1280 B each
    __shared__ unsigned short sH2h[16 * SKH], sH2l[16 * SKH];
    __shared__ float sG[16 * 132];  // 8448 B; also head scratch

    const int tid = threadIdx.x;
    const int wave = tid >> 6, lane = tid & 63;
    const int quad = lane >> 4, l15 = lane & 15;
    const int bBase = blockIdx.x * 16;

    // ---- register B-fragments ----------------------------------------------
    // Wih0: [128 gates][158] -> bX[ks][nt][hi/lo], k = ks*32 + quad*8 + j
    short8 bX[5][2][2];
#pragma unroll
    for (int nt = 0; nt < 2; ++nt) {
        const int n = wave * 32 + nt * 16 + l15;
#pragma unroll
        for (int ks = 0; ks < 5; ++ks) {
            float wv[8];
#pragma unroll
            for (int j = 0; j < 8; ++j) {
                int k = ks * 32 + quad * 8 + j;
                wv[j] = (k < Fn) ? Wih0[n * Fn + k] : 0.f;
            }
            cvt8(wv, bX[ks][nt][0], bX[ks][nt][1]);
        }
    }
    // recurrent: 0=Whh0, 1=Wih1, 2=Whh1 (each [128][32])
    short8 bW[3][2][2];
    const float* Wp[3] = {Whh0, Wih1, Whh1};
#pragma unroll
    for (int m = 0; m < 3; ++m)
#pragma unroll
        for (int nt = 0; nt < 2; ++nt) {
            const int n = wave * 32 + nt * 16 + l15;
            const float* wp = Wp[m] + n * Hn + quad * 8;
            float4 q0 = *(const float4*)(wp);
            float4 q1 = *(const float4*)(wp + 4);
            float wv[8] = {q0.x, q0.y, q0.z, q0.w, q1.x, q1.y, q1.z, q1.w};
            cvt8(wv, bW[m][nt][0], bW[m][nt][1]);
        }

    // ---- x staging: per-thread fixed (row, col) pairs, 5 float2 per thread --
    // 16 rows x 79 float2 = 1264 elements
    const float* xp[5];
    int soff[5];  // LDS word offset: row*84 + c
    bool act[5];
#pragma unroll
    for (int r = 0; r < 5; ++r) {
        int i = tid + r * 256;
        act[r] = (i < 1264);
        int row = i / 79, c = i - row * 79;
        if (!act[r]) { row = 0; c = 0; }
        soff[r] = row * (SKX / 2) + c;
        xp[r] = x + (size_t)(bBase + row) * (Tn * Fn) + 2 * c;
    }
    auto stage = [&](const float2* v, int buf) {
        unsigned* dh = (unsigned*)sXh + buf * (16 * SKX / 2);
        unsigned* dl = (unsigned*)sXl + buf * (16 * SKX / 2);
#pragma unroll
        for (int r = 0; r < 5; ++r) {
            if (act[r]) {
                unsigned short h0 = bf16r(v[r].x), h1 = bf16r(v[r].y);
                unsigned short l0 = bf16r(v[r].x - bf16f(h0));
                unsigned short l1 = bf16r(v[r].y - bf16f(h1));
                dh[soff[r]] = (unsigned)h0 | ((unsigned)h1 << 16);
                dl[soff[r]] = (unsigned)l0 | ((unsigned)l1 << 16);
            }
        }
    };

    // zero h state, zero x pad columns (k=158,159) in both buffers
    for (int i = tid; i < 320; i += 256) {
        ((unsigned*)sH1h)[i] = 0; ((unsigned*)sH1l)[i] = 0;
        ((unsigned*)sH2h)[i] = 0; ((unsigned*)sH2l)[i] = 0;
    }
    if (tid < 32) {
        int buf = tid >> 4, row = tid & 15;
        ((unsigned*)sXh)[buf * 1344 + row * 84 + 79] = 0;
        ((unsigned*)sXl)[buf * 1344 + row * 84 + 79] = 0;
    }

    // stage t=0 into buf 0
    {
        float2 v[5];
#pragma unroll
        for (int r = 0; r < 5; ++r) {
            v[r] = act[r] ? *(const float2*)xp[r] : make_float2(0.f, 0.f);
            xp[r] += Fn;
        }
        stage(v, 0);
    }

    const int aOffH = l15 * SKH + quad * 8;          // h A-frag short offset
    const int urow = tid >> 4, uj = (tid & 15) * 2;  // update mapping
    float c1x = 0.f, c1y = 0.f, c2x = 0.f, c2y = 0.f;
    __syncthreads();

    for (int t = 0; t < Tn; ++t) {
        const int buf = t & 1;
        // prefetch x(t+1) into registers
        float2 xr[5];
        if (t < Tn - 1) {
#pragma unroll
            for (int r = 0; r < 5; ++r) {
                xr[r] = act[r] ? *(const float2*)xp[r] : make_float2(0.f, 0.f);
                xp[r] += Fn;
            }
        }

        // ---- layer-1 gates: x_t @ Wih0^T + h1_old @ Whh0^T ----
        {
            const unsigned short* bxh = sXh + buf * (16 * SKX);
            const unsigned short* bxl = sXl + buf * (16 * SKX);
            short8 a1h = *(const short8*)(sH1h + aOffH);
            short8 a1l = *(const short8*)(sH1l + aOffH);
            floatx4 acc[2] = {};
#pragma unroll
            for (int ks = 0; ks < 5; ++ks) {
                const int off = l15 * SKX + ks * 32 + quad * 8;
                short8 xh = *(const short8*)(bxh + off);
                short8 xl = *(const short8*)(bxl + off);
#pragma unroll
                for (int nt = 0; nt < 2; ++nt) {
                    acc[nt] = __builtin_amdgcn_mfma_f32_16x16x32_bf16(xh, bX[ks][nt][0], acc[nt], 0, 0, 0);
                    acc[nt] = __builtin_amdgcn_mfma_f32_16x16x32_bf16(xh, bX[ks][nt][1], acc[nt], 0, 0, 0);
                    acc[nt] = __builtin_amdgcn_mfma_f32_16x16x32_bf16(xl, bX[ks][nt][0], acc[nt], 0, 0, 0);
                }
            }
#pragma unroll
            for (int nt = 0; nt < 2; ++nt) {
                acc[nt] = __builtin_amdgcn_mfma_f32_16x16x32_bf16(a1h, bW[0][nt][0], acc[nt], 0, 0, 0);
                acc[nt] = __builtin_amdgcn_mfma_f32_16x16x32_bf16(a1h, bW[0][nt][1], acc[nt], 0, 0, 0);
                acc[nt] = __builtin_amdgcn_mfma_f32_16x16x32_bf16(a1l, bW[0][nt][0], acc[nt], 0, 0, 0);
            }
#pragma unroll
            for (int nt = 0; nt < 2; ++nt)
#pragma unroll
                for (int reg = 0; reg < 4; ++reg)
                    sG[(quad * 4 + reg) * 132 + wave * 32 + nt * 16 + l15] = acc[nt][reg];
        }
        __syncthreads();  // B1: gates1 visible; h1_old & x-buf reads done

        {  // ---- update layer 1
            const float* g0 = sG + urow * 132 + uj;
            float2 ig = *(const float2*)(g0);
            float2 fg = *(const float2*)(g0 + 32);
            float2 gg = *(const float2*)(g0 + 64);
            float2 og = *(const float2*)(g0 + 96);
            c1x = sigm_(fg.x) * c1x + sigm_(ig.x) * tanh_(gg.x);
            c1y = sigm_(fg.y) * c1y + sigm_(ig.y) * tanh_(gg.y);
            float h0 = sigm_(og.x) * tanh_(c1x);
            float h1v = sigm_(og.y) * tanh_(c1y);
            unsigned short h0h = bf16r(h0), h1h = bf16r(h1v);
            unsigned short h0l = bf16r(h0 - bf16f(h0h)), h1l = bf16r(h1v - bf16f(h1h));
            *(unsigned*)(sH1h + urow * SKH + uj) = (unsigned)h0h | ((unsigned)h1h << 16);
            *(unsigned*)(sH1l + urow * SKH + uj) = (unsigned)h0l | ((unsigned)h1l << 16);
        }
        __syncthreads();  // B2: h1_new visible

        // ---- layer-2 gates: h1_new @ Wih1^T + h2_old @ Whh1^T ----
        {
            short8 a1h = *(const short8*)(sH1h + aOffH);
            short8 a1l = *(const short8*)(sH1l + aOffH);
            short8 a2h = *(const short8*)(sH2h + aOffH);
            short8 a2l = *(const short8*)(sH2l + aOffH);
            floatx4 acc[2] = {};
#pragma unroll
            for (int nt = 0; nt < 2; ++nt) {
                acc[nt] = __builtin_amdgcn_mfma_f32_16x16x32_bf16(a1h, bW[1][nt][0], acc[nt], 0, 0, 0);
                acc[nt] = __builtin_amdgcn_mfma_f32_16x16x32_bf16(a1h, bW[1][nt][1], acc[nt], 0, 0, 0);
                acc[nt] = __builtin_amdgcn_mfma_f32_16x16x32_bf16(a1l, bW[1][nt][0], acc[nt], 0, 0, 0);
                acc[nt] = __builtin_amdgcn_mfma_f32_16x16x32_bf16(a2h, bW[2][nt][0], acc[nt], 0, 0, 0);
                acc[nt] = __builtin_amdgcn_mfma_f32_16x16x32_bf16(a2h, bW[2][nt][1], acc[nt], 0, 0, 0);
                acc[nt] = __builtin_amdgcn_mfma_f32_16x16x32_bf16(a2l, bW[2][nt][0], acc[nt], 0, 0, 0);
            }
#pragma unroll
            for (int nt = 0; nt < 2; ++nt)
#pragma unroll
                for (int reg = 0; reg < 4; ++reg)
                    sG[(quad * 4 + reg) * 132 + wave * 32 + nt * 16 + l15] = acc[nt][reg];
        }
        // stage x(t+1) into the other buffer (no reader until after B4)
        if (t < Tn - 1) stage(xr, buf ^ 1);
        __syncthreads();  // B3: gates2 visible; h2_old reads done

        {  // ---- update layer 2
            const float* g0 = sG + urow * 132 + uj;
            float2 ig = *(const float2*)(g0);
            float2 fg = *(const float2*)(g0 + 32);
            float2 gg = *(const float2*)(g0 + 64);
            float2 og = *(const float2*)(g0 + 96);
            c2x = sigm_(fg.x) * c2x + sigm_(ig.x) * tanh_(gg.x);
            c2y = sigm_(fg.y) * c2y + sigm_(ig.y) * tanh_(gg.y);
            float h0 = sigm_(og.x) * tanh_(c2x);
            float h1v = sigm_(og.y) * tanh_(c2y);
            unsigned short h0h = bf16r(h0), h1h = bf16r(h1v);
            unsigned short h0l = bf16r(h0 - bf16f(h0h)), h1l = bf16r(h1v - bf16f(h1h));
            *(unsigned*)(sH2h + urow * SKH + uj) = (unsigned)h0h | ((unsigned)h1h << 16);
            *(unsigned*)(sH2l + urow * SKH + uj) = (unsigned)h0l | ((unsigned)h1l << 16);
        }
        __syncthreads();  // B4: h2_new + staged x(t+1) visible
    }

    // ---- head on final c1, c2: y = relu(c @ W1^T + b1) @ W2^T
    float* sC = sG;  // [2][16][33]
    *(float2*)(sC + urow * 33 + uj) = make_float2(c1x, c1y);
    *(float2*)(sC + 528 + urow * 33 + uj) = make_float2(c2x, c2y);
    __syncthreads();
    if (tid < 32) {
        int l = tid >> 4, b = tid & 15;
        const float* cc = sC + l * 528 + b * 33;
        float y = 0.f;
#pragma unroll 1
        for (int q = 0; q < 16; ++q) {
            float s = b1[q];
#pragma unroll
            for (int j = 0; j < 32; ++j) s = fmaf(cc[j], W1[q * 32 + j], s);
            y = fmaf(fmaxf(s, 0.f), W2[q], y);
        }
        out[l * Bn + bBase + b] = y;
    }
}

extern "C" void kernel_launch(void* const* d_in, const int* in_sizes, int n_in,
                              void* d_out, int out_size, void* d_ws, size_t ws_size,
                              hipStream_t stream) {
    const float* x    = (const float*)d_in[0];
    const float* Wih0 = (const float*)d_in[1];
    const float* Whh0 = (const float*)d_in[2];
    const float* Wih1 = (const float*)d_in[3];
    const float* Whh1 = (const float*)d_in[4];
    const float* W1   = (const float*)d_in[5];
    const float* b1   = (const float*)d_in[6];
    const float* W2   = (const float*)d_in[7];
    float* out = (float*)d_out;

    lstm2_fused_kernel<<<Bn / 16, 256, 0, stream>>>(x, Wih0, Whh0, Wih1, Whh1,
                                                    W1, b1, W2, out);
}